// Round 11
// baseline (449.573 us; speedup 1.0000x reference)
//
#include <hip/hip_runtime.h>
#include <hip/hip_fp16.h>
#include <math.h>

#define LEAKY 0.2f
#define HDIM 64
#define EPB 4096            // edges per block (sort pass)
#define TPB1 256
#define PERT (EPB / TPB1)   // 16 edges per thread
#define RANGE 1024          // nodes per bucket
#define RSH 10
#define KMAX 128            // K<=128 => N<=131072 => col fits in 17 bits
#define NSUB 4              // sub-cursors per bucket
#define NPART 4             // record-range parts per sub
#define NSLICE (NSUB * NPART)   // 16 reduce blocks per bucket
#define FS2 262144.0f       // 2^18 overflow-path fixed-point scale
#define INVFS2 (1.0f / 262144.0f)

// single-u64 accumulator record: [x:24 | y:20 | z:20]  (R10-verified, absmax ok)
//  xb = rn(mx*2^8)+2^18 (2^18 spacing encodes COUNT); yb/zb = rn(m*2^10)+2^14
//  decode: c=(xf+2^17)>>18 ; xsum=xf-c*2^18 ; y/zsum=f-c*2^14
#define XBIAS_REC 262144u   // 2^18
#define YZBIAS_REC 16384u   // 2^14
#define SX 256.0f
#define SYZ 1024.0f
#define INV_SX (1.0f / 256.0f)
#define INV_SYZ (1.0f / 1024.0f)

typedef unsigned int u32x4 __attribute__((ext_vector_type(4)));
typedef unsigned long long u64;

// sort record: u32 = (lid(row) << 17) | col — sort carries NO coordinates.

// tanh(v) = 1 - 2/(exp2(v*2*log2e)+1); exact saturation, ~1e-6 rel err
__device__ __forceinline__ float fast_tanh(float v) {
    float e = __builtin_amdgcn_exp2f(v * 2.88539008178f);
    return 1.0f - 2.0f * __builtin_amdgcn_rcpf(e + 1.0f);
}

// slow-path edge MLP, deliberately NOT inlined (bp1==0 here, never executes)
__device__ __noinline__ float edge_eo_slow(float rad,
                                           const float* sW1, const float* sb1,
                                           const float* sW2) {
    float a = 0.f;
    #pragma unroll 1
    for (int k = 0; k < HDIM; k++) {
        float h = fmaf(rad, sW1[k], sb1[k]);
        h = (h > 0.f) ? h : LEAKY * h;
        a = fmaf(sW2[k], h, a);
    }
    return fast_tanh(a);
}

// half-packed coords + consts precompute + acc4/cursor/done zero-init (one dispatch)
__global__ void repack_h_kernel(const float* __restrict__ x, uint2* __restrict__ xh, int N,
                                const float* __restrict__ Wp1, const float* __restrict__ bp1,
                                const float* __restrict__ Wp2, float* __restrict__ consts,
                                uint4* __restrict__ acc4, unsigned* __restrict__ cursor, int K) {
    int i = blockIdx.x * blockDim.x + threadIdx.x;
    if (i < N) {
        unsigned hx = __half_as_ushort(__float2half(x[3*i]));
        unsigned hy = __half_as_ushort(__float2half(x[3*i+1]));
        unsigned hz = __half_as_ushort(__float2half(x[3*i+2]));
        xh[i] = make_uint2((hy << 16) | hx, hz);
        acc4[i] = make_uint4(0u, 0u, 0u, 0u);
    }
    if (blockIdx.x == 0) {
        if (threadIdx.x < 64) {
            int k = threadIdx.x;   // one wave: shuffle reduction valid
            float w1 = Wp1[k];
            float slope = (w1 >= 0.f) ? 1.f : LEAKY;
            float c = Wp2[k] * w1 * slope;
            float bnz = (bp1[k] != 0.f) ? 1.f : 0.f;
            #pragma unroll
            for (int off = 32; off > 0; off >>= 1) {
                c += __shfl_down(c, off, 64);
                bnz += __shfl_down(bnz, off, 64);
            }
            if (k == 0) { consts[0] = c; consts[1] = bnz; }
        }
        // zero cursor (NSUB*KMAX) + done (KMAX), contiguous
        for (int k = threadIdx.x; k < NSUB * KMAX + KMAX; k += 256) cursor[k] = 0u;
    }
}

// overflow fallback (~8-sigma never): compute one edge from xh, add into acc4
// with unbiased signed fixed-point (u32 wrap-exact). Not inlined.
__device__ __noinline__ void overflow_edge(unsigned rec, unsigned b_, const uint2* __restrict__ xh,
                              float C, bool slow,
                              const float* __restrict__ Wp1, const float* __restrict__ bp1,
                              const float* __restrict__ Wp2, unsigned* __restrict__ acc4) {
    unsigned lid = rec >> 17, col = rec & 0x1FFFFu;
    unsigned row = b_ * RANGE + lid;
    uint2 ga = xh[row], gb = xh[col];
    float ax = __half2float(__ushort_as_half((unsigned short)(ga.x & 0xFFFF)));
    float ay = __half2float(__ushort_as_half((unsigned short)(ga.x >> 16)));
    float az = __half2float(__ushort_as_half((unsigned short)(ga.y & 0xFFFF)));
    float bx = __half2float(__ushort_as_half((unsigned short)(gb.x & 0xFFFF)));
    float by = __half2float(__ushort_as_half((unsigned short)(gb.x >> 16)));
    float bz = __half2float(__ushort_as_half((unsigned short)(gb.y & 0xFFFF)));
    float dx = ax - bx, dy = ay - by, dz = az - bz;
    float rad = sqrtf(dx*dx + dy*dy + dz*dz);
    float eo;
    if (!slow) {
        eo = fast_tanh(C * rad);
    } else {
        float a = 0.f;
        for (int k = 0; k < HDIM; k++) {
            float h = fmaf(rad, Wp1[k], bp1[k]);
            h = (h > 0.f) ? h : LEAKY * h;
            a = fmaf(Wp2[k], h, a);
        }
        eo = fast_tanh(a);
    }
    atomicAdd(&acc4[4*row + 0], (unsigned)__float2int_rn(dx * eo * FS2));
    atomicAdd(&acc4[4*row + 1], (unsigned)__float2int_rn(dy * eo * FS2));
    atomicAdd(&acc4[4*row + 2], (unsigned)__float2int_rn(dz * eo * FS2));
    atomicAdd(&acc4[4*row + 3], 1u);
}

// ---- PASS 1 (R9/R10-verified sort6): free-rank + bucket_of coalesced write-out.
__global__ __launch_bounds__(TPB1) void sort6_kernel(
        const int* __restrict__ ei,
        const uint2* __restrict__ xh,           // overflow path only
        const float* __restrict__ Wp1, const float* __restrict__ bp1,
        const float* __restrict__ Wp2, const float* __restrict__ consts,
        unsigned* __restrict__ cursor, unsigned* __restrict__ acc4,
        unsigned* __restrict__ recs, int E, int K, unsigned csub) {
    __shared__ unsigned stage[EPB];              // 16 KB
    __shared__ unsigned char bucket_of[EPB];     // 4 KB
    __shared__ unsigned hist[KMAX];
    __shared__ unsigned scanv[KMAX + 1];
    __shared__ unsigned gstart[KMAX];
    const float C = consts[0];
    const bool slow = (consts[1] != 0.f);
    const unsigned sub = (unsigned)blockIdx.x & (NSUB - 1);
    for (int k = threadIdx.x; k < K; k += TPB1) hist[k] = 0;
    __syncthreads();   // B0

    const size_t base = (size_t)blockIdx.x * EPB;
    const unsigned t = threadIdx.x;
    unsigned rc[PERT];
    unsigned meta[PERT];   // (bk << 12) | rank   (rank < 4096, bk < 128)
    if (base + EPB <= (size_t)E && (E & 3) == 0) {
        const int4* pr = (const int4*)(ei + base);
        const int4* pc = (const int4*)(ei + (size_t)E + base);
        #pragma unroll
        for (int q = 0; q < PERT / 4; q++) {
            int4 rv = pr[t + q * TPB1];
            int4 cv = pc[t + q * TPB1];
            rc[4*q+0] = (((unsigned)rv.x & (RANGE-1)) << 17) | (unsigned)cv.x;
            rc[4*q+1] = (((unsigned)rv.y & (RANGE-1)) << 17) | (unsigned)cv.y;
            rc[4*q+2] = (((unsigned)rv.z & (RANGE-1)) << 17) | (unsigned)cv.z;
            rc[4*q+3] = (((unsigned)rv.w & (RANGE-1)) << 17) | (unsigned)cv.w;
            unsigned b0 = (unsigned)rv.x >> RSH;
            unsigned b1 = (unsigned)rv.y >> RSH;
            unsigned b2 = (unsigned)rv.z >> RSH;
            unsigned b3 = (unsigned)rv.w >> RSH;
            meta[4*q+0] = (b0 << 12) | atomicAdd(&hist[b0], 1u);
            meta[4*q+1] = (b1 << 12) | atomicAdd(&hist[b1], 1u);
            meta[4*q+2] = (b2 << 12) | atomicAdd(&hist[b2], 1u);
            meta[4*q+3] = (b3 << 12) | atomicAdd(&hist[b3], 1u);
        }
    } else {
        #pragma unroll
        for (int i = 0; i < PERT; i++) {
            size_t e = base + (size_t)i * TPB1 + t;
            meta[i] = 0xFFFFFFFFu;
            if (e < (size_t)E) {
                unsigned r = (unsigned)ei[e];
                unsigned c = (unsigned)ei[(size_t)E + e];
                rc[i] = ((r & (RANGE-1)) << 17) | c;
                unsigned b_ = r >> RSH;
                meta[i] = (b_ << 12) | atomicAdd(&hist[b_], 1u);
            }
        }
    }
    __syncthreads();   // B1: hist complete, ranks assigned
    // reserve global segments (waves 0-1); return consumed after scatter
    unsigned res = 0;
    if (t < (unsigned)K) {
        unsigned myc = hist[t];
        if (myc) res = atomicAdd(&cursor[t * NSUB + sub], myc);
    }
    // wave 3: 128-wide exclusive scan of hist via shuffles
    if (t >= 192) {
        int l = t - 192;
        unsigned origA = (l < K) ? hist[l] : 0u;
        unsigned origB = (l + 64 < K) ? hist[l + 64] : 0u;
        unsigned a = origA, b = origB;
        #pragma unroll
        for (int off = 1; off < 64; off <<= 1) {
            unsigned va = __shfl_up(a, off, 64);
            unsigned vb = __shfl_up(b, off, 64);
            if (l >= off) { a += va; b += vb; }
        }
        unsigned totA = __shfl(a, 63, 64);
        unsigned grand = totA + __shfl(b, 63, 64);
        scanv[l] = a - origA;
        scanv[l + 64] = totA + b - origB;
        if (l == 63) scanv[K] = grand;
    }
    __syncthreads();   // B2: scanv ready
    // deterministic scatter into stage: slot = scanv[bk] + rank (no atomics)
    #pragma unroll
    for (int i = 0; i < PERT; i++) {
        if (meta[i] != 0xFFFFFFFFu) {
            unsigned bk_ = meta[i] >> 12;
            unsigned slot = scanv[bk_] + (meta[i] & 0xFFFu);
            stage[slot] = rc[i];
            bucket_of[slot] = (unsigned char)bk_;
        }
    }
    if (t < (unsigned)K) gstart[t] = res;   // atomic-return wait lands here
    __syncthreads();   // B3
    // coalesced write-out into (bucket,sub) regions
    unsigned total = scanv[K];
    for (unsigned j = t; j < total; j += TPB1) {
        unsigned b_ = bucket_of[j];
        unsigned off = gstart[b_] + (j - scanv[b_]);
        if (off < csub) recs[(size_t)(b_ * NSUB + sub) * csub + off] = stage[j];
        else            overflow_edge(stage[j], (unsigned)b_, xh, C, slow,
                                      Wp1, bp1, Wp2, acc4);
    }
}

// ---- PASS 2 (R11): gather + MLP + single-u64 LDS atomic accumulate.
// Changes vs R10: (a) 4-quad gather-first inner loop — all 16 xh[col] gathers
// issued before any use (reduce is gather-latency-bound, R10 post-mortem);
// (b) last-arriving block per bucket finalizes the node output (release/acquire
// via threadfence + device-scope atomic) — deletes the node_merge dispatch.
__global__ __launch_bounds__(256, 4) void reduce11_kernel(
        const unsigned* __restrict__ recs, const unsigned* __restrict__ cursor,
        const uint2* __restrict__ xh,
        const float* __restrict__ Wp1, const float* __restrict__ bp1,
        const float* __restrict__ Wp2, const float* __restrict__ consts,
        u64* __restrict__ slices, unsigned* __restrict__ done,
        const float* __restrict__ x, const float* __restrict__ vel_norm,
        const float* __restrict__ vel,
        const float* __restrict__ W1, const float* __restrict__ b1,
        const float* __restrict__ W2, const float* __restrict__ b2,
        const uint4* __restrict__ acc4, float* __restrict__ out,
        int N, int K, unsigned csub) {
    __shared__ u64 accA[RANGE];                  // 8 KB
    __shared__ uint2 sxh[RANGE];                 // 8 KB bucket-row coords
    __shared__ float sW1[HDIM], sb1[HDIM], sW2[HDIM];
    __shared__ unsigned lastFlag;
    const int b = blockIdx.x / NSLICE;
    const int s = blockIdx.x % NSLICE;
    const int r = s & (NSUB - 1);      // sub-region
    const int p = s >> 2;              // quarter of the sub-region
    const float C = consts[0];
    const bool slow = (consts[1] != 0.f);
    const int nbase = b * RANGE;
    if (slow) {
        for (int k = threadIdx.x; k < HDIM; k += 256) {
            sW1[k] = Wp1[k]; sb1[k] = bp1[k]; sW2[k] = Wp2[k];
        }
    }
    for (int i = threadIdx.x; i < RANGE; i += 256) {
        accA[i] = 0ull;
        int src = nbase + i;
        sxh[i] = xh[(src < N) ? src : 0];
    }
    __syncthreads();
    unsigned cnt = cursor[b * NSUB + r];
    if (cnt > csub) cnt = csub;        // overflow edges went straight to acc4
    unsigned quads = (cnt + 3) >> 2;
    unsigned perq = (quads + 3) >> 2;
    unsigned q0 = (unsigned)p * perq;
    unsigned q1 = q0 + perq; if (q1 > quads) q1 = quads;
    const u32x4* rb4 = (const u32x4*)(recs + (size_t)(b * NSUB + r) * csub);

    // unguarded gather is safe: col masked to 17 bits -> within workspace
    #define PROC2(rec, gbv, idx)                                                   \
        if ((idx) < cnt) {                                                         \
            unsigned lid_ = (rec) >> 17;                                           \
            uint2 ga = sxh[lid_];                                                  \
            uint2 gb = (gbv);                                                      \
            float ax = __half2float(__ushort_as_half((unsigned short)(ga.x & 0xFFFF))); \
            float ay = __half2float(__ushort_as_half((unsigned short)(ga.x >> 16)));    \
            float az = __half2float(__ushort_as_half((unsigned short)(ga.y & 0xFFFF))); \
            float bx = __half2float(__ushort_as_half((unsigned short)(gb.x & 0xFFFF))); \
            float by = __half2float(__ushort_as_half((unsigned short)(gb.x >> 16)));    \
            float bz = __half2float(__ushort_as_half((unsigned short)(gb.y & 0xFFFF))); \
            float dx = ax - bx, dy = ay - by, dz = az - bz;                        \
            float rad = sqrtf(dx*dx + dy*dy + dz*dz);                              \
            float eo = slow ? edge_eo_slow(rad, sW1, sb1, sW2)                     \
                            : fast_tanh(C * rad);                                  \
            unsigned xb = (unsigned)(__float2int_rn(dx * eo * SX) + (int)XBIAS_REC);   \
            unsigned yb = (unsigned)(__float2int_rn(dy * eo * SYZ) + (int)YZBIAS_REC); \
            unsigned zb = (unsigned)(__float2int_rn(dz * eo * SYZ) + (int)YZBIAS_REC); \
            u64 packed = ((u64)xb << 40) | ((u64)yb << 20) | (u64)zb;              \
            atomicAdd(&accA[lid_], packed);                                        \
        }

    unsigned q = q0 + threadIdx.x;
    while (q + 768 < q1) {
        u32x4 v0 = __builtin_nontemporal_load(&rb4[q]);
        u32x4 v1 = __builtin_nontemporal_load(&rb4[q + 256]);
        u32x4 v2 = __builtin_nontemporal_load(&rb4[q + 512]);
        u32x4 v3 = __builtin_nontemporal_load(&rb4[q + 768]);
        // all 16 col-gathers issued before first use
        uint2 g0  = xh[v0.x & 0x1FFFFu], g1  = xh[v0.y & 0x1FFFFu];
        uint2 g2  = xh[v0.z & 0x1FFFFu], g3  = xh[v0.w & 0x1FFFFu];
        uint2 g4  = xh[v1.x & 0x1FFFFu], g5  = xh[v1.y & 0x1FFFFu];
        uint2 g6  = xh[v1.z & 0x1FFFFu], g7  = xh[v1.w & 0x1FFFFu];
        uint2 g8  = xh[v2.x & 0x1FFFFu], g9  = xh[v2.y & 0x1FFFFu];
        uint2 g10 = xh[v2.z & 0x1FFFFu], g11 = xh[v2.w & 0x1FFFFu];
        uint2 g12 = xh[v3.x & 0x1FFFFu], g13 = xh[v3.y & 0x1FFFFu];
        uint2 g14 = xh[v3.z & 0x1FFFFu], g15 = xh[v3.w & 0x1FFFFu];
        unsigned i0 = 4 * q, i1 = 4 * (q + 256), i2 = 4 * (q + 512), i3 = 4 * (q + 768);
        PROC2(v0.x, g0,  i0);     PROC2(v0.y, g1,  i0 + 1);
        PROC2(v0.z, g2,  i0 + 2); PROC2(v0.w, g3,  i0 + 3);
        PROC2(v1.x, g4,  i1);     PROC2(v1.y, g5,  i1 + 1);
        PROC2(v1.z, g6,  i1 + 2); PROC2(v1.w, g7,  i1 + 3);
        PROC2(v2.x, g8,  i2);     PROC2(v2.y, g9,  i2 + 1);
        PROC2(v2.z, g10, i2 + 2); PROC2(v2.w, g11, i2 + 3);
        PROC2(v3.x, g12, i3);     PROC2(v3.y, g13, i3 + 1);
        PROC2(v3.z, g14, i3 + 2); PROC2(v3.w, g15, i3 + 3);
        q += 1024;
    }
    while (q < q1) {
        u32x4 v = __builtin_nontemporal_load(&rb4[q]);
        uint2 g0 = xh[v.x & 0x1FFFFu], g1 = xh[v.y & 0x1FFFFu];
        uint2 g2 = xh[v.z & 0x1FFFFu], g3 = xh[v.w & 0x1FFFFu];
        unsigned i0 = 4 * q;
        PROC2(v.x, g0, i0);     PROC2(v.y, g1, i0 + 1);
        PROC2(v.z, g2, i0 + 2); PROC2(v.w, g3, i0 + 3);
        q += 256;
    }
    #undef PROC2
    __syncthreads();
    for (int i = threadIdx.x; i < RANGE; i += 256) {
        int node = nbase + i;
        if (node < N) slices[(size_t)s * N + node] = accA[i];
    }
    // ---- last-block finalize (replaces node_merge dispatch) ----
    __threadfence();               // release: slice writes visible device-wide
    __syncthreads();               // all threads fenced before the mark
    if (threadIdx.x == 0) {
        unsigned v = atomicAdd(&done[b], 1u);   // device-scope
        lastFlag = (v == NSLICE - 1) ? 1u : 0u;
    }
    __syncthreads();
    if (!lastFlag) return;
    __threadfence();               // acquire: see all 15 other blocks' slices
    for (int k = threadIdx.x; k < HDIM; k += 256) {
        sW1[k] = W1[k]; sb1[k] = b1[k]; sW2[k] = W2[k];   // node-MLP weights
    }
    __syncthreads();
    const float b2v = b2[0];
    for (int i = threadIdx.x; i < RANGE; i += 256) {
        int node = nbase + i;
        if (node >= N) continue;
        long long sxll = 0, syll = 0, szll = 0;
        unsigned sc = 0;
        #pragma unroll
        for (int s2 = 0; s2 < NSLICE; s2++) {
            u64 f = slices[(size_t)s2 * N + node];
            unsigned xf = (unsigned)(f >> 40);            // 24 bits
            unsigned yf = (unsigned)(f >> 20) & 0xFFFFFu; // 20 bits
            unsigned zf = (unsigned)f & 0xFFFFFu;         // 20 bits
            unsigned cs = (xf + 131072u) >> 18;           // count decode
            sxll += (long long)xf - ((long long)cs << 18);
            syll += (long long)yf - ((long long)cs << 14);
            szll += (long long)zf - ((long long)cs << 14);
            sc += cs;
        }
        uint4 a4 = acc4[node];  // overflow contribution (normally zero)
        float cntf = (float)(sc + a4.w);
        float sx = (float)sxll * INV_SX  + (float)(int)a4.x * INVFS2;
        float sy = (float)syll * INV_SYZ + (float)(int)a4.y * INVFS2;
        float sz = (float)szll * INV_SYZ + (float)(int)a4.z * INVFS2;
        float vn = vel_norm[node];
        float a = b2v;
        #pragma unroll
        for (int k = 0; k < HDIM; k++) {
            float h = fmaf(vn, sW1[k], sb1[k]);
            h = (h > 0.f) ? h : LEAKY * h;
            a = fmaf(sW2[k], h, a);
        }
        float inv = 1.0f / fmaxf(cntf, 1.0f);
        out[3*node]     = x[3*node]     + sx * inv + vel[3*node]     * a;
        out[3*node + 1] = x[3*node + 1] + sy * inv + vel[3*node + 1] * a;
        out[3*node + 2] = x[3*node + 2] + sz * inv + vel[3*node + 2] * a;
    }
}

// ---- plain-atomic fallback path (K > KMAX or tiny workspace) ----
__global__ void precompute_kernel(const float* __restrict__ Wp1,
                                  const float* __restrict__ bp1,
                                  const float* __restrict__ Wp2,
                                  float* __restrict__ consts) {
    int k = threadIdx.x;
    float w1 = Wp1[k];
    float slope = (w1 >= 0.f) ? 1.f : LEAKY;
    float c = Wp2[k] * w1 * slope;
    float bnz = (bp1[k] != 0.f) ? 1.f : 0.f;
    #pragma unroll
    for (int off = 32; off > 0; off >>= 1) {
        c += __shfl_down(c, off, 64);
        bnz += __shfl_down(bnz, off, 64);
    }
    if (k == 0) { consts[0] = c; consts[1] = bnz; }
}

__global__ void edge_atomic_kernel(const float* __restrict__ x, const int* __restrict__ ei,
                                   const float* __restrict__ Wp1, const float* __restrict__ bp1,
                                   const float* __restrict__ Wp2, const float* __restrict__ consts,
                                   float* __restrict__ acc, int E) {
    __shared__ float sW1[HDIM], sb1[HDIM], sW2[HDIM];
    const float C = consts[0];
    const bool slow = (consts[1] != 0.f);
    if (slow) {
        for (int k = threadIdx.x; k < HDIM; k += blockDim.x) {
            sW1[k] = Wp1[k]; sb1[k] = bp1[k]; sW2[k] = Wp2[k];
        }
        __syncthreads();
    }
    int e = blockIdx.x * blockDim.x + threadIdx.x;
    if (e >= E) return;
    int r = ei[e];
    int c = ei[E + e];
    float dx = x[3*r] - x[3*c];
    float dy = x[3*r+1] - x[3*c+1];
    float dz = x[3*r+2] - x[3*c+2];
    float rad = sqrtf(dx*dx + dy*dy + dz*dz);
    float eo;
    if (!slow) {
        eo = fast_tanh(C * rad);
    } else {
        float a = 0.f;
        for (int k = 0; k < HDIM; k++) {
            float h = fmaf(rad, sW1[k], sb1[k]);
            h = (h > 0.f) ? h : LEAKY * h;
            a = fmaf(sW2[k], h, a);
        }
        eo = fast_tanh(a);
    }
    float* basep = acc + ((size_t)r << 2);
    atomicAdd(basep + 0, dx * eo);
    atomicAdd(basep + 1, dy * eo);
    atomicAdd(basep + 2, dz * eo);
    atomicAdd(basep + 3, 1.f);
}

__global__ void node_kernel(const float* __restrict__ x, const float* __restrict__ vel_norm,
                            const float* __restrict__ vel,
                            const float* __restrict__ W1, const float* __restrict__ b1,
                            const float* __restrict__ W2, const float* __restrict__ b2,
                            const float4* __restrict__ slices,
                            float* __restrict__ out, int N, int S) {
    __shared__ float sW1[HDIM], sb1[HDIM], sW2[HDIM];
    for (int k = threadIdx.x; k < HDIM; k += blockDim.x) {
        sW1[k] = W1[k]; sb1[k] = b1[k]; sW2[k] = W2[k];
    }
    __syncthreads();
    int i = blockIdx.x * blockDim.x + threadIdx.x;
    if (i >= N) return;
    float sx = 0.f, sy = 0.f, sz = 0.f, sc = 0.f;
    for (int s = 0; s < S; s++) {
        float4 v = slices[(size_t)s * N + i];
        sx += v.x; sy += v.y; sz += v.z; sc += v.w;
    }
    float vn = vel_norm[i];
    float a = b2[0];
    #pragma unroll
    for (int k = 0; k < HDIM; k++) {
        float h = fmaf(vn, sW1[k], sb1[k]);
        h = (h > 0.f) ? h : LEAKY * h;
        a = fmaf(sW2[k], h, a);
    }
    float inv = 1.0f / fmaxf(sc, 1.0f);
    out[3*i]     = x[3*i]     + sx * inv + vel[3*i]     * a;
    out[3*i + 1] = x[3*i + 1] + sy * inv + vel[3*i + 1] * a;
    out[3*i + 2] = x[3*i + 2] + sz * inv + vel[3*i + 2] * a;
}

extern "C" void kernel_launch(void* const* d_in, const int* in_sizes, int n_in,
                              void* d_out, int out_size, void* d_ws, size_t ws_size,
                              hipStream_t stream) {
    const float* x        = (const float*)d_in[0];
    const float* vel_norm = (const float*)d_in[1];
    const float* vel      = (const float*)d_in[2];
    const int*   ei       = (const int*)  d_in[3];
    const float* W1       = (const float*)d_in[4];
    const float* b1       = (const float*)d_in[5];
    const float* W2       = (const float*)d_in[6];
    const float* b2       = (const float*)d_in[7];
    const float* Wp1      = (const float*)d_in[8];
    const float* bp1      = (const float*)d_in[9];
    const float* Wp2      = (const float*)d_in[10];

    const int N = in_sizes[0] / 3;
    const int E = in_sizes[3] / 2;
    const int K = (N + RANGE - 1) / RANGE;
    const int nblk = (E + EPB - 1) / EPB;

    // per-(bucket,sub) capacity: mean + 1024 (~8 sigma); overflow -> direct atomics
    unsigned csub = (unsigned)(E / (K * NSUB)) + 1024u;
    csub = (csub + 63u) & ~63u;

    // layout: [recs: K*NSUB*csub*4] [slices: NSLICE*N*8] [xh: N*8] [acc4: N*16]
    //         [cursor: NSUB*KMAX | done: KMAX] [consts]
    size_t rec_bytes = (size_t)K * NSUB * csub * sizeof(unsigned);
    size_t sp_slices = (rec_bytes + 15) & ~(size_t)15;
    size_t sp_xh     = sp_slices + (size_t)NSLICE * N * sizeof(u64);
    size_t sp_acc    = (sp_xh + (size_t)N * sizeof(uint2) + 15) & ~(size_t)15;
    size_t sp_cur    = sp_acc + (size_t)N * sizeof(uint4);
    size_t sp_const  = (sp_cur + (size_t)(NSUB * KMAX + KMAX) * sizeof(unsigned) + 15) & ~(size_t)15;
    size_t need      = sp_const + 32;

    if (K <= KMAX && ws_size >= need) {
        unsigned* recs   = (unsigned*)d_ws;
        u64*      slices = (u64*)     ((char*)d_ws + sp_slices);
        uint2*    xh     = (uint2*)   ((char*)d_ws + sp_xh);
        unsigned* acc4   = (unsigned*)((char*)d_ws + sp_acc);
        unsigned* cursor = (unsigned*)((char*)d_ws + sp_cur);
        unsigned* done   = cursor + NSUB * KMAX;
        float*    consts = (float*)   ((char*)d_ws + sp_const);

        repack_h_kernel<<<(N + 255) / 256, 256, 0, stream>>>(
            x, xh, N, Wp1, bp1, Wp2, consts, (uint4*)acc4, cursor, K);
        sort6_kernel<<<nblk, TPB1, 0, stream>>>(
            ei, xh, Wp1, bp1, Wp2, consts, cursor, acc4, recs, E, K, csub);
        reduce11_kernel<<<K * NSLICE, 256, 0, stream>>>(
            recs, cursor, xh, Wp1, bp1, Wp2, consts, slices, done,
            x, vel_norm, vel, W1, b1, W2, b2,
            (const uint4*)acc4, (float*)d_out, N, K, csub);
    } else {
        float* acc    = (float*)d_ws;
        float* consts = (float*)((char*)d_ws + (size_t)N * sizeof(float4));
        hipMemsetAsync(d_ws, 0, (size_t)N * sizeof(float4) + 32, stream);
        precompute_kernel<<<1, 64, 0, stream>>>(Wp1, bp1, Wp2, consts);
        edge_atomic_kernel<<<(E + 255) / 256, 256, 0, stream>>>(x, ei, Wp1, bp1, Wp2,
                                                                consts, acc, E);
        node_kernel<<<(N + 255) / 256, 256, 0, stream>>>(x, vel_norm, vel, W1, b1, W2, b2,
                                                         (const float4*)acc, (float*)d_out, N, 1);
    }
}

// Round 12
// 182.597 us; speedup vs baseline: 2.4621x; 2.4621x over previous
//
#include <hip/hip_runtime.h>
#include <hip/hip_fp16.h>
#include <math.h>

#define LEAKY 0.2f
#define HDIM 64
#define EPB 4096            // edges per block (sort pass)
#define TPB1 256
#define PERT (EPB / TPB1)   // 16 edges per thread
#define RANGE 1024          // nodes per bucket
#define RSH 10
#define KMAX 128            // K<=128 => N<=131072 => col fits in 17 bits
#define NSUB 4              // sub-cursors per bucket
#define NPART 4             // record-range parts per sub
#define NSLICE (NSUB * NPART)   // 16 reduce blocks per bucket
#define FS2 262144.0f       // 2^18 overflow-path fixed-point scale
#define INVFS2 (1.0f / 262144.0f)

// single-u64 accumulator record: [x:24 | y:20 | z:20]  (R10-verified, absmax ok)
//  xb = rn(mx*2^8)+2^18 (2^18 spacing encodes COUNT); yb/zb = rn(m*2^10)+2^14
//  decode: c=(xf+2^17)>>18 ; xsum=xf-c*2^18 ; y/zsum=f-c*2^14
#define XBIAS_REC 262144u   // 2^18
#define YZBIAS_REC 16384u   // 2^14
#define SX 256.0f
#define SYZ 1024.0f
#define INV_SX (1.0f / 256.0f)
#define INV_SYZ (1.0f / 1024.0f)

typedef unsigned int u32x4 __attribute__((ext_vector_type(4)));
typedef unsigned long long u64;

// sort record: u32 = (lid(row) << 17) | col — sort carries NO coordinates.

// tanh(v) = 1 - 2/(exp2(v*2*log2e)+1); exact saturation, ~1e-6 rel err
__device__ __forceinline__ float fast_tanh(float v) {
    float e = __builtin_amdgcn_exp2f(v * 2.88539008178f);
    return 1.0f - 2.0f * __builtin_amdgcn_rcpf(e + 1.0f);
}

// slow-path edge MLP, deliberately NOT inlined (bp1==0 here, never executes)
__device__ __noinline__ float edge_eo_slow(float rad,
                                           const float* sW1, const float* sb1,
                                           const float* sW2) {
    float a = 0.f;
    #pragma unroll 1
    for (int k = 0; k < HDIM; k++) {
        float h = fmaf(rad, sW1[k], sb1[k]);
        h = (h > 0.f) ? h : LEAKY * h;
        a = fmaf(sW2[k], h, a);
    }
    return fast_tanh(a);
}

// half-packed coords + consts precompute + acc4/cursor zero-init (one dispatch)
__global__ void repack_h_kernel(const float* __restrict__ x, uint2* __restrict__ xh, int N,
                                const float* __restrict__ Wp1, const float* __restrict__ bp1,
                                const float* __restrict__ Wp2, float* __restrict__ consts,
                                uint4* __restrict__ acc4, unsigned* __restrict__ cursor, int K) {
    int i = blockIdx.x * blockDim.x + threadIdx.x;
    if (i < N) {
        unsigned hx = __half_as_ushort(__float2half(x[3*i]));
        unsigned hy = __half_as_ushort(__float2half(x[3*i+1]));
        unsigned hz = __half_as_ushort(__float2half(x[3*i+2]));
        xh[i] = make_uint2((hy << 16) | hx, hz);
        acc4[i] = make_uint4(0u, 0u, 0u, 0u);
    }
    if (blockIdx.x == 0) {
        if (threadIdx.x < 64) {
            int k = threadIdx.x;   // one wave: shuffle reduction valid
            float w1 = Wp1[k];
            float slope = (w1 >= 0.f) ? 1.f : LEAKY;
            float c = Wp2[k] * w1 * slope;
            float bnz = (bp1[k] != 0.f) ? 1.f : 0.f;
            #pragma unroll
            for (int off = 32; off > 0; off >>= 1) {
                c += __shfl_down(c, off, 64);
                bnz += __shfl_down(bnz, off, 64);
            }
            if (k == 0) { consts[0] = c; consts[1] = bnz; }
        }
        for (int k = threadIdx.x; k < NSUB * K; k += 256) cursor[k] = 0u;
    }
}

// overflow fallback (~8-sigma never): compute one edge from xh, add into acc4
// with unbiased signed fixed-point (u32 wrap-exact). Not inlined.
__device__ __noinline__ void overflow_edge(unsigned rec, unsigned b_, const uint2* __restrict__ xh,
                              float C, bool slow,
                              const float* __restrict__ Wp1, const float* __restrict__ bp1,
                              const float* __restrict__ Wp2, unsigned* __restrict__ acc4) {
    unsigned lid = rec >> 17, col = rec & 0x1FFFFu;
    unsigned row = b_ * RANGE + lid;
    uint2 ga = xh[row], gb = xh[col];
    float ax = __half2float(__ushort_as_half((unsigned short)(ga.x & 0xFFFF)));
    float ay = __half2float(__ushort_as_half((unsigned short)(ga.x >> 16)));
    float az = __half2float(__ushort_as_half((unsigned short)(ga.y & 0xFFFF)));
    float bx = __half2float(__ushort_as_half((unsigned short)(gb.x & 0xFFFF)));
    float by = __half2float(__ushort_as_half((unsigned short)(gb.x >> 16)));
    float bz = __half2float(__ushort_as_half((unsigned short)(gb.y & 0xFFFF)));
    float dx = ax - bx, dy = ay - by, dz = az - bz;
    float rad = sqrtf(dx*dx + dy*dy + dz*dz);
    float eo;
    if (!slow) {
        eo = fast_tanh(C * rad);
    } else {
        float a = 0.f;
        for (int k = 0; k < HDIM; k++) {
            float h = fmaf(rad, Wp1[k], bp1[k]);
            h = (h > 0.f) ? h : LEAKY * h;
            a = fmaf(Wp2[k], h, a);
        }
        eo = fast_tanh(a);
    }
    atomicAdd(&acc4[4*row + 0], (unsigned)__float2int_rn(dx * eo * FS2));
    atomicAdd(&acc4[4*row + 1], (unsigned)__float2int_rn(dy * eo * FS2));
    atomicAdd(&acc4[4*row + 2], (unsigned)__float2int_rn(dz * eo * FS2));
    atomicAdd(&acc4[4*row + 3], 1u);
}

// ---- PASS 1 (R9-verified sort6): free-rank + bucket_of coalesced write-out.
__global__ __launch_bounds__(TPB1) void sort6_kernel(
        const int* __restrict__ ei,
        const uint2* __restrict__ xh,           // overflow path only
        const float* __restrict__ Wp1, const float* __restrict__ bp1,
        const float* __restrict__ Wp2, const float* __restrict__ consts,
        unsigned* __restrict__ cursor, unsigned* __restrict__ acc4,
        unsigned* __restrict__ recs, int E, int K, unsigned csub) {
    __shared__ unsigned stage[EPB];              // 16 KB
    __shared__ unsigned char bucket_of[EPB];     // 4 KB
    __shared__ unsigned hist[KMAX];
    __shared__ unsigned scanv[KMAX + 1];
    __shared__ unsigned gstart[KMAX];
    const float C = consts[0];
    const bool slow = (consts[1] != 0.f);
    const unsigned sub = (unsigned)blockIdx.x & (NSUB - 1);
    for (int k = threadIdx.x; k < K; k += TPB1) hist[k] = 0;
    __syncthreads();   // B0

    const size_t base = (size_t)blockIdx.x * EPB;
    const unsigned t = threadIdx.x;
    unsigned rc[PERT];
    unsigned meta[PERT];   // (bk << 12) | rank   (rank < 4096, bk < 128)
    if (base + EPB <= (size_t)E && (E & 3) == 0) {
        const int4* pr = (const int4*)(ei + base);
        const int4* pc = (const int4*)(ei + (size_t)E + base);
        #pragma unroll
        for (int q = 0; q < PERT / 4; q++) {
            int4 rv = pr[t + q * TPB1];
            int4 cv = pc[t + q * TPB1];
            rc[4*q+0] = (((unsigned)rv.x & (RANGE-1)) << 17) | (unsigned)cv.x;
            rc[4*q+1] = (((unsigned)rv.y & (RANGE-1)) << 17) | (unsigned)cv.y;
            rc[4*q+2] = (((unsigned)rv.z & (RANGE-1)) << 17) | (unsigned)cv.z;
            rc[4*q+3] = (((unsigned)rv.w & (RANGE-1)) << 17) | (unsigned)cv.w;
            unsigned b0 = (unsigned)rv.x >> RSH;
            unsigned b1 = (unsigned)rv.y >> RSH;
            unsigned b2 = (unsigned)rv.z >> RSH;
            unsigned b3 = (unsigned)rv.w >> RSH;
            meta[4*q+0] = (b0 << 12) | atomicAdd(&hist[b0], 1u);
            meta[4*q+1] = (b1 << 12) | atomicAdd(&hist[b1], 1u);
            meta[4*q+2] = (b2 << 12) | atomicAdd(&hist[b2], 1u);
            meta[4*q+3] = (b3 << 12) | atomicAdd(&hist[b3], 1u);
        }
    } else {
        #pragma unroll
        for (int i = 0; i < PERT; i++) {
            size_t e = base + (size_t)i * TPB1 + t;
            meta[i] = 0xFFFFFFFFu;
            if (e < (size_t)E) {
                unsigned r = (unsigned)ei[e];
                unsigned c = (unsigned)ei[(size_t)E + e];
                rc[i] = ((r & (RANGE-1)) << 17) | c;
                unsigned b_ = r >> RSH;
                meta[i] = (b_ << 12) | atomicAdd(&hist[b_], 1u);
            }
        }
    }
    __syncthreads();   // B1: hist complete, ranks assigned
    // reserve global segments (waves 0-1); return consumed after scatter
    unsigned res = 0;
    if (t < (unsigned)K) {
        unsigned myc = hist[t];
        if (myc) res = atomicAdd(&cursor[t * NSUB + sub], myc);
    }
    // wave 3: 128-wide exclusive scan of hist via shuffles
    if (t >= 192) {
        int l = t - 192;
        unsigned origA = (l < K) ? hist[l] : 0u;
        unsigned origB = (l + 64 < K) ? hist[l + 64] : 0u;
        unsigned a = origA, b = origB;
        #pragma unroll
        for (int off = 1; off < 64; off <<= 1) {
            unsigned va = __shfl_up(a, off, 64);
            unsigned vb = __shfl_up(b, off, 64);
            if (l >= off) { a += va; b += vb; }
        }
        unsigned totA = __shfl(a, 63, 64);
        unsigned grand = totA + __shfl(b, 63, 64);
        scanv[l] = a - origA;
        scanv[l + 64] = totA + b - origB;
        if (l == 63) scanv[K] = grand;
    }
    __syncthreads();   // B2: scanv ready
    // deterministic scatter into stage: slot = scanv[bk] + rank (no atomics)
    #pragma unroll
    for (int i = 0; i < PERT; i++) {
        if (meta[i] != 0xFFFFFFFFu) {
            unsigned bk_ = meta[i] >> 12;
            unsigned slot = scanv[bk_] + (meta[i] & 0xFFFu);
            stage[slot] = rc[i];
            bucket_of[slot] = (unsigned char)bk_;
        }
    }
    if (t < (unsigned)K) gstart[t] = res;   // atomic-return wait lands here
    __syncthreads();   // B3
    // coalesced write-out into (bucket,sub) regions
    unsigned total = scanv[K];
    for (unsigned j = t; j < total; j += TPB1) {
        unsigned b_ = bucket_of[j];
        unsigned off = gstart[b_] + (j - scanv[b_]);
        if (off < csub) recs[(size_t)(b_ * NSUB + sub) * csub + off] = stage[j];
        else            overflow_edge(stage[j], (unsigned)b_, xh, C, slow,
                                      Wp1, bp1, Wp2, acc4);
    }
}

// ---- PASS 2 (R10-verified reduce10): ONE u64 LDS atomic per edge — count rides
// in the x-field's 2^18 bias. sxh preload keeps row gathers off the memory path.
__global__ __launch_bounds__(256, 4) void reduce10_kernel(
        const unsigned* __restrict__ recs, const unsigned* __restrict__ cursor,
        const uint2* __restrict__ xh,
        const float* __restrict__ Wp1, const float* __restrict__ bp1,
        const float* __restrict__ Wp2, const float* __restrict__ consts,
        u64* __restrict__ slices, int N, int K, unsigned csub) {
    __shared__ u64 accA[RANGE];                  // 8 KB
    __shared__ uint2 sxh[RANGE];                 // 8 KB bucket-row coords
    __shared__ float sW1[HDIM], sb1[HDIM], sW2[HDIM];
    const int b = blockIdx.x / NSLICE;
    const int s = blockIdx.x % NSLICE;
    const int r = s & (NSUB - 1);      // sub-region
    const int p = s >> 2;              // quarter of the sub-region
    const float C = consts[0];
    const bool slow = (consts[1] != 0.f);
    const int nbase = b * RANGE;
    if (slow) {
        for (int k = threadIdx.x; k < HDIM; k += 256) {
            sW1[k] = Wp1[k]; sb1[k] = bp1[k]; sW2[k] = Wp2[k];
        }
    }
    for (int i = threadIdx.x; i < RANGE; i += 256) {
        accA[i] = 0ull;
        int src = nbase + i;
        sxh[i] = xh[(src < N) ? src : 0];
    }
    __syncthreads();
    unsigned cnt = cursor[b * NSUB + r];
    if (cnt > csub) cnt = csub;        // overflow edges went straight to acc4
    unsigned quads = (cnt + 3) >> 2;
    unsigned perq = (quads + 3) >> 2;
    unsigned q0 = (unsigned)p * perq;
    unsigned q1 = q0 + perq; if (q1 > quads) q1 = quads;
    const u32x4* rb4 = (const u32x4*)(recs + (size_t)(b * NSUB + r) * csub);

    #define PROC_REC(rec, idx)                                                     \
        if ((idx) < cnt) {                                                         \
            unsigned lid_ = (rec) >> 17, col_ = (rec) & 0x1FFFFu;                  \
            uint2 ga = sxh[lid_];                                                  \
            uint2 gb = xh[col_];                                                   \
            float ax = __half2float(__ushort_as_half((unsigned short)(ga.x & 0xFFFF))); \
            float ay = __half2float(__ushort_as_half((unsigned short)(ga.x >> 16)));    \
            float az = __half2float(__ushort_as_half((unsigned short)(ga.y & 0xFFFF))); \
            float bx = __half2float(__ushort_as_half((unsigned short)(gb.x & 0xFFFF))); \
            float by = __half2float(__ushort_as_half((unsigned short)(gb.x >> 16)));    \
            float bz = __half2float(__ushort_as_half((unsigned short)(gb.y & 0xFFFF))); \
            float dx = ax - bx, dy = ay - by, dz = az - bz;                        \
            float rad = sqrtf(dx*dx + dy*dy + dz*dz);                              \
            float eo = slow ? edge_eo_slow(rad, sW1, sb1, sW2)                     \
                            : fast_tanh(C * rad);                                  \
            unsigned xb = (unsigned)(__float2int_rn(dx * eo * SX) + (int)XBIAS_REC);   \
            unsigned yb = (unsigned)(__float2int_rn(dy * eo * SYZ) + (int)YZBIAS_REC); \
            unsigned zb = (unsigned)(__float2int_rn(dz * eo * SYZ) + (int)YZBIAS_REC); \
            u64 packed = ((u64)xb << 40) | ((u64)yb << 20) | (u64)zb;              \
            atomicAdd(&accA[lid_], packed);                                        \
        }

    unsigned q = q0 + threadIdx.x;
    while (q + 256 < q1) {
        u32x4 v0 = __builtin_nontemporal_load(&rb4[q]);
        u32x4 v1 = __builtin_nontemporal_load(&rb4[q + 256]);
        unsigned i0 = 4 * q, i1 = 4 * (q + 256);
        PROC_REC(v0.x, i0); PROC_REC(v0.y, i0 + 1);
        PROC_REC(v0.z, i0 + 2); PROC_REC(v0.w, i0 + 3);
        PROC_REC(v1.x, i1); PROC_REC(v1.y, i1 + 1);
        PROC_REC(v1.z, i1 + 2); PROC_REC(v1.w, i1 + 3);
        q += 512;
    }
    while (q < q1) {
        u32x4 v = __builtin_nontemporal_load(&rb4[q]);
        unsigned i0 = 4 * q;
        PROC_REC(v.x, i0); PROC_REC(v.y, i0 + 1);
        PROC_REC(v.z, i0 + 2); PROC_REC(v.w, i0 + 3);
        q += 256;
    }
    #undef PROC_REC
    __syncthreads();
    for (int i = threadIdx.x; i < RANGE; i += 256) {
        int node = nbase + i;
        if (node < N) slices[(size_t)s * N + node] = accA[i];
    }
}

// final node pass: decode per-slice packed sums (count from x-bias), merge
// overflow acc4, fuse velocity MLP
__global__ void node_merge_kernel(const float* __restrict__ x,
                                  const float* __restrict__ vel_norm,
                                  const float* __restrict__ vel,
                                  const float* __restrict__ W1, const float* __restrict__ b1,
                                  const float* __restrict__ W2, const float* __restrict__ b2,
                                  const u64* __restrict__ slices,
                                  const uint4* __restrict__ acc4,
                                  float* __restrict__ out, int N) {
    __shared__ float sW1[HDIM], sb1[HDIM], sW2[HDIM];
    for (int k = threadIdx.x; k < HDIM; k += blockDim.x) {
        sW1[k] = W1[k]; sb1[k] = b1[k]; sW2[k] = W2[k];
    }
    __syncthreads();
    int i = blockIdx.x * blockDim.x + threadIdx.x;
    if (i >= N) return;
    long long sxll = 0, syll = 0, szll = 0;
    unsigned sc = 0;
    #pragma unroll
    for (int s = 0; s < NSLICE; s++) {
        u64 f = slices[(size_t)s * N + i];
        unsigned xf = (unsigned)(f >> 40);            // 24 bits
        unsigned yf = (unsigned)(f >> 20) & 0xFFFFFu; // 20 bits
        unsigned zf = (unsigned)f & 0xFFFFFu;         // 20 bits
        unsigned cs = (xf + 131072u) >> 18;           // count decode
        sxll += (long long)xf - ((long long)cs << 18);
        syll += (long long)yf - ((long long)cs << 14);
        szll += (long long)zf - ((long long)cs << 14);
        sc += cs;
    }
    uint4 a4 = acc4[i];  // overflow contribution (normally zero; 2^18 signed fixed)
    float cntf = (float)(sc + a4.w);
    float sx = (float)sxll * INV_SX  + (float)(int)a4.x * INVFS2;
    float sy = (float)syll * INV_SYZ + (float)(int)a4.y * INVFS2;
    float sz = (float)szll * INV_SYZ + (float)(int)a4.z * INVFS2;
    float vn = vel_norm[i];
    float a = b2[0];
    #pragma unroll
    for (int k = 0; k < HDIM; k++) {
        float h = fmaf(vn, sW1[k], sb1[k]);
        h = (h > 0.f) ? h : LEAKY * h;
        a = fmaf(sW2[k], h, a);
    }
    float inv = 1.0f / fmaxf(cntf, 1.0f);
    out[3*i]     = x[3*i]     + sx * inv + vel[3*i]     * a;
    out[3*i + 1] = x[3*i + 1] + sy * inv + vel[3*i + 1] * a;
    out[3*i + 2] = x[3*i + 2] + sz * inv + vel[3*i + 2] * a;
}

// ---- plain-atomic fallback path (K > KMAX or tiny workspace) ----
__global__ void precompute_kernel(const float* __restrict__ Wp1,
                                  const float* __restrict__ bp1,
                                  const float* __restrict__ Wp2,
                                  float* __restrict__ consts) {
    int k = threadIdx.x;
    float w1 = Wp1[k];
    float slope = (w1 >= 0.f) ? 1.f : LEAKY;
    float c = Wp2[k] * w1 * slope;
    float bnz = (bp1[k] != 0.f) ? 1.f : 0.f;
    #pragma unroll
    for (int off = 32; off > 0; off >>= 1) {
        c += __shfl_down(c, off, 64);
        bnz += __shfl_down(bnz, off, 64);
    }
    if (k == 0) { consts[0] = c; consts[1] = bnz; }
}

__global__ void edge_atomic_kernel(const float* __restrict__ x, const int* __restrict__ ei,
                                   const float* __restrict__ Wp1, const float* __restrict__ bp1,
                                   const float* __restrict__ Wp2, const float* __restrict__ consts,
                                   float* __restrict__ acc, int E) {
    __shared__ float sW1[HDIM], sb1[HDIM], sW2[HDIM];
    const float C = consts[0];
    const bool slow = (consts[1] != 0.f);
    if (slow) {
        for (int k = threadIdx.x; k < HDIM; k += blockDim.x) {
            sW1[k] = Wp1[k]; sb1[k] = bp1[k]; sW2[k] = Wp2[k];
        }
        __syncthreads();
    }
    int e = blockIdx.x * blockDim.x + threadIdx.x;
    if (e >= E) return;
    int r = ei[e];
    int c = ei[E + e];
    float dx = x[3*r] - x[3*c];
    float dy = x[3*r+1] - x[3*c+1];
    float dz = x[3*r+2] - x[3*c+2];
    float rad = sqrtf(dx*dx + dy*dy + dz*dz);
    float eo;
    if (!slow) {
        eo = fast_tanh(C * rad);
    } else {
        float a = 0.f;
        for (int k = 0; k < HDIM; k++) {
            float h = fmaf(rad, sW1[k], sb1[k]);
            h = (h > 0.f) ? h : LEAKY * h;
            a = fmaf(sW2[k], h, a);
        }
        eo = fast_tanh(a);
    }
    float* basep = acc + ((size_t)r << 2);
    atomicAdd(basep + 0, dx * eo);
    atomicAdd(basep + 1, dy * eo);
    atomicAdd(basep + 2, dz * eo);
    atomicAdd(basep + 3, 1.f);
}

__global__ void node_kernel(const float* __restrict__ x, const float* __restrict__ vel_norm,
                            const float* __restrict__ vel,
                            const float* __restrict__ W1, const float* __restrict__ b1,
                            const float* __restrict__ W2, const float* __restrict__ b2,
                            const float4* __restrict__ slices,
                            float* __restrict__ out, int N, int S) {
    __shared__ float sW1[HDIM], sb1[HDIM], sW2[HDIM];
    for (int k = threadIdx.x; k < HDIM; k += blockDim.x) {
        sW1[k] = W1[k]; sb1[k] = b1[k]; sW2[k] = W2[k];
    }
    __syncthreads();
    int i = blockIdx.x * blockDim.x + threadIdx.x;
    if (i >= N) return;
    float sx = 0.f, sy = 0.f, sz = 0.f, sc = 0.f;
    for (int s = 0; s < S; s++) {
        float4 v = slices[(size_t)s * N + i];
        sx += v.x; sy += v.y; sz += v.z; sc += v.w;
    }
    float vn = vel_norm[i];
    float a = b2[0];
    #pragma unroll
    for (int k = 0; k < HDIM; k++) {
        float h = fmaf(vn, sW1[k], sb1[k]);
        h = (h > 0.f) ? h : LEAKY * h;
        a = fmaf(sW2[k], h, a);
    }
    float inv = 1.0f / fmaxf(sc, 1.0f);
    out[3*i]     = x[3*i]     + sx * inv + vel[3*i]     * a;
    out[3*i + 1] = x[3*i + 1] + sy * inv + vel[3*i + 1] * a;
    out[3*i + 2] = x[3*i + 2] + sz * inv + vel[3*i + 2] * a;
}

extern "C" void kernel_launch(void* const* d_in, const int* in_sizes, int n_in,
                              void* d_out, int out_size, void* d_ws, size_t ws_size,
                              hipStream_t stream) {
    const float* x        = (const float*)d_in[0];
    const float* vel_norm = (const float*)d_in[1];
    const float* vel      = (const float*)d_in[2];
    const int*   ei       = (const int*)  d_in[3];
    const float* W1       = (const float*)d_in[4];
    const float* b1       = (const float*)d_in[5];
    const float* W2       = (const float*)d_in[6];
    const float* b2       = (const float*)d_in[7];
    const float* Wp1      = (const float*)d_in[8];
    const float* bp1      = (const float*)d_in[9];
    const float* Wp2      = (const float*)d_in[10];

    const int N = in_sizes[0] / 3;
    const int E = in_sizes[3] / 2;
    const int K = (N + RANGE - 1) / RANGE;
    const int nblk = (E + EPB - 1) / EPB;

    // per-(bucket,sub) capacity: mean + 1024 (~8 sigma); overflow -> direct atomics
    unsigned csub = (unsigned)(E / (K * NSUB)) + 1024u;
    csub = (csub + 63u) & ~63u;

    // layout: [recs: K*NSUB*csub*4] [slices: NSLICE*N*8] [xh: N*8] [acc4: N*16] [cursor] [consts]
    size_t rec_bytes = (size_t)K * NSUB * csub * sizeof(unsigned);
    size_t sp_slices = (rec_bytes + 15) & ~(size_t)15;
    size_t sp_xh     = sp_slices + (size_t)NSLICE * N * sizeof(u64);
    size_t sp_acc    = (sp_xh + (size_t)N * sizeof(uint2) + 15) & ~(size_t)15;
    size_t sp_cur    = sp_acc + (size_t)N * sizeof(uint4);
    size_t sp_const  = (sp_cur + (size_t)NSUB * KMAX * sizeof(unsigned) + 15) & ~(size_t)15;
    size_t need      = sp_const + 32;

    if (K <= KMAX && ws_size >= need) {
        unsigned* recs   = (unsigned*)d_ws;
        u64*      slices = (u64*)     ((char*)d_ws + sp_slices);
        uint2*    xh     = (uint2*)   ((char*)d_ws + sp_xh);
        unsigned* acc4   = (unsigned*)((char*)d_ws + sp_acc);
        unsigned* cursor = (unsigned*)((char*)d_ws + sp_cur);
        float*    consts = (float*)   ((char*)d_ws + sp_const);

        repack_h_kernel<<<(N + 255) / 256, 256, 0, stream>>>(
            x, xh, N, Wp1, bp1, Wp2, consts, (uint4*)acc4, cursor, K);
        sort6_kernel<<<nblk, TPB1, 0, stream>>>(
            ei, xh, Wp1, bp1, Wp2, consts, cursor, acc4, recs, E, K, csub);
        reduce10_kernel<<<K * NSLICE, 256, 0, stream>>>(
            recs, cursor, xh, Wp1, bp1, Wp2, consts, slices, N, K, csub);
        node_merge_kernel<<<(N + 255) / 256, 256, 0, stream>>>(
            x, vel_norm, vel, W1, b1, W2, b2, slices, (const uint4*)acc4,
            (float*)d_out, N);
    } else {
        float* acc    = (float*)d_ws;
        float* consts = (float*)((char*)d_ws + (size_t)N * sizeof(float4));
        hipMemsetAsync(d_ws, 0, (size_t)N * sizeof(float4) + 32, stream);
        precompute_kernel<<<1, 64, 0, stream>>>(Wp1, bp1, Wp2, consts);
        edge_atomic_kernel<<<(E + 255) / 256, 256, 0, stream>>>(x, ei, Wp1, bp1, Wp2,
                                                                consts, acc, E);
        node_kernel<<<(N + 255) / 256, 256, 0, stream>>>(x, vel_norm, vel, W1, b1, W2, b2,
                                                         (const float4*)acc, (float*)d_out, N, 1);
    }
}